// Round 4
// baseline (246.882 us; speedup 1.0000x reference)
//
#include <hip/hip_runtime.h>
#include <math.h>

namespace {
constexpr int BB = 8;
constexpr int CH = 256;
constexpr int NN = 4096;
}

typedef float f32x4 __attribute__((ext_vector_type(4)));
typedef short bf16x8 __attribute__((ext_vector_type(8)));
typedef unsigned short us8 __attribute__((ext_vector_type(8)));

#define MFMA16(a, b, c) __builtin_amdgcn_mfma_f32_16x16x32_bf16(a, b, c, 0, 0, 0)

__device__ __forceinline__ unsigned short f2bf(float x) {
    unsigned int u = __float_as_uint(x);
    u += 0x7fffu + ((u >> 16) & 1u);
    return (unsigned short)(u >> 16);
}
__device__ __forceinline__ float bf2f(unsigned short h) {
    return __uint_as_float(((unsigned int)h) << 16);
}
__device__ __forceinline__ void gload16(const void* g, void* l) {
    __builtin_amdgcn_global_load_lds(
        (const __attribute__((address_space(1))) unsigned int*)g,
        (__attribute__((address_space(3))) unsigned int*)l, 16, 0, 0);
}

// ---------------------------------------------------------------------------
// Kernel 0: split W (wq|wk|wv, 320x256) into bf16 hi/lo.
// ---------------------------------------------------------------------------
__global__ __launch_bounds__(256) void wsplit_kernel(
    const float* __restrict__ wq, const float* __restrict__ wk,
    const float* __restrict__ wv,
    unsigned short* __restrict__ wh, unsigned short* __restrict__ wl)
{
    int idx = blockIdx.x * 256 + threadIdx.x;   // 0..81919
    float v;
    if (idx < 8192)       v = wq[idx];
    else if (idx < 16384) v = wk[idx - 8192];
    else                  v = wv[idx - 16384];
    unsigned short hi = f2bf(v);
    wh[idx] = hi;
    wl[idx] = f2bf(v - bf2f(hi));
}

// ---------------------------------------------------------------------------
// Kernel 1: fused transpose + proj GEMM (MFMA, 3-term hi/lo split).
// Block = (b, 64-pixel tile). Phase 1 stages X fp32 [64c][64n] per channel
// group and transpose-converts in-LDS to bf16 hi/lo [64n][256c] (chunk-XOR
// swizzled). Phase 2: K-loop MFMA. Epilogue -> qh/ql/kh/kl [b][n][32],
// vt [b][c][n].
// ---------------------------------------------------------------------------
#define PJ_XH 0
#define PJ_XL 32768
#define PJ_ST 65536     // 16 KB fp32 stage (aliased by QK in epilogue)
#define PJ_QK 65536
#define PJ_VE 0

__global__ __launch_bounds__(256, 2) void proj_kernel(
    const float* __restrict__ x,
    const unsigned short* __restrict__ wh, const unsigned short* __restrict__ wl,
    const float* __restrict__ bq, const float* __restrict__ bk,
    const float* __restrict__ bv,
    unsigned short* __restrict__ qh, unsigned short* __restrict__ ql,
    unsigned short* __restrict__ kh, unsigned short* __restrict__ kl,
    unsigned short* __restrict__ vt)
{
    __shared__ __align__(16) unsigned char smem[81920];
    const int t    = threadIdx.x;
    const int lane = t & 63;
    const int w    = t >> 6;
    const int l16  = lane & 15;
    const int quad = lane >> 4;
    const int b    = blockIdx.x >> 6;
    const int n0   = (blockIdx.x & 63) << 6;

    // ---- phase 1: stage + transpose-convert, 4 channel groups of 64
    const unsigned char* xB = (const unsigned char*)x + ((size_t)b * 256 * NN + n0) * 4;
    const int n = t & 63;
    #pragma unroll 1
    for (int cg = 0; cg < 4; ++cg) {
        __syncthreads();   // stage region free (prev convert done)
        #pragma unroll
        for (int j = 0; j < 4; ++j) {
            int idx = j * 256 + t;
            int cr = idx >> 4, nch = idx & 15;
            gload16(xB + (size_t)(cg * 64 + cr) * NN * 4 + nch * 16,
                    smem + PJ_ST + idx * 16);
        }
        __syncthreads();
        #pragma unroll
        for (int it = 0; it < 2; ++it) {
            int o = (t >> 6) + 4 * it;            // c-octet within group
            us8 h8, l8;
            #pragma unroll
            for (int j = 0; j < 8; ++j) {
                float v = *(const float*)(smem + PJ_ST + (o * 8 + j) * 256 + n * 4);
                unsigned short hi = f2bf(v);
                h8[j] = hi;
                l8[j] = f2bf(v - bf2f(hi));
            }
            int pch = (cg * 8 + o) ^ (n & 7);     // match K-loop read swizzle
            *(us8*)(smem + PJ_XH + n * 512 + pch * 16) = h8;
            *(us8*)(smem + PJ_XL + n * 512 + pch * 16) = l8;
        }
    }
    __syncthreads();

    // ---- phase 2: K-loop. Wave w owns och-tiles w*5..w*5+4 (0-63 q/k, 64-319 v)
    f32x4 acc[5][4] = {};
    #pragma unroll 1
    for (int kc = 0; kc < 8; ++kc) {
        bf16x8 ah[5], al[5];
        #pragma unroll
        for (int i = 0; i < 5; ++i) {
            int och = (w * 5 + i) * 16 + l16;
            ah[i] = *(const bf16x8*)(wh + och * 256 + kc * 32 + quad * 8);
            al[i] = *(const bf16x8*)(wl + och * 256 + kc * 32 + quad * 8);
        }
        #pragma unroll
        for (int nt = 0; nt < 4; ++nt) {
            int roff = (nt * 16 + l16) * 512 + (((kc * 4 + quad) ^ (l16 & 7)) * 16);
            bf16x8 bh = *(const bf16x8*)(smem + PJ_XH + roff);
            bf16x8 bl = *(const bf16x8*)(smem + PJ_XL + roff);
            #pragma unroll
            for (int i = 0; i < 5; ++i) {
                acc[i][nt] = MFMA16(ah[i], bh, acc[i][nt]);
                acc[i][nt] = MFMA16(al[i], bh, acc[i][nt]);
                acc[i][nt] = MFMA16(ah[i], bl, acc[i][nt]);
            }
        }
    }
    __syncthreads();   // LDS reads done; alias epilogue regions

    // ---- epilogue
    #pragma unroll
    for (int i = 0; i < 5; ++i) {
        int tile = w * 5 + i;
        if (tile < 4) {  // q/k tiles (wave 0 only)
            #pragma unroll
            for (int r = 0; r < 4; ++r) {
                int och = tile * 16 + quad * 4 + r;
                float bias = (och < 32) ? bq[och] : bk[och - 32];
                int arr = (och < 32) ? 0 : 2;
                int oq = och & 31;
                #pragma unroll
                for (int nt = 0; nt < 4; ++nt) {
                    float val = acc[i][nt][r] + bias;
                    unsigned short hi = f2bf(val);
                    unsigned short lo = f2bf(val - bf2f(hi));
                    *(unsigned short*)(smem + PJ_QK + arr * 4096 + (nt * 16 + l16) * 64 + oq * 2) = hi;
                    *(unsigned short*)(smem + PJ_QK + (arr + 1) * 4096 + (nt * 16 + l16) * 64 + oq * 2) = lo;
                }
            }
        } else {          // v tiles
            #pragma unroll
            for (int r = 0; r < 4; ++r) {
                int voch = tile * 16 + quad * 4 + r - 64;
                float bias = bv[voch];
                #pragma unroll
                for (int nt = 0; nt < 4; ++nt) {
                    *(unsigned short*)(smem + PJ_VE + voch * 136 + (nt * 16 + l16) * 2)
                        = f2bf(acc[i][nt][r] + bias);
                }
            }
        }
    }
    __syncthreads();

    {   // copy-out q/k: 4 arrays x 64 rows x 64B
        unsigned short* dsts[4] = { qh, ql, kh, kl };
        int arr = t >> 6, rn = t & 63;
        unsigned short* dst = dsts[arr] + ((size_t)b * NN + n0 + rn) * 32;
        #pragma unroll
        for (int i = 0; i < 4; ++i)
            *(us8*)(dst + i * 8) = *(const us8*)(smem + PJ_QK + arr * 4096 + rn * 64 + i * 16);
    }
    #pragma unroll
    for (int p = 0; p < 4; ++p) {   // copy-out v: 256 rows x 128B
        int voch = p * 64 + (t >> 2), piece = t & 3;
        unsigned short* dst = vt + ((size_t)b * CH + voch) * NN + n0 + piece * 16;
        *(us8*)(dst)     = *(const us8*)(smem + PJ_VE + voch * 136 + piece * 32);
        *(us8*)(dst + 8) = *(const us8*)(smem + PJ_VE + voch * 136 + piece * 32 + 16);
    }
}

// ---------------------------------------------------------------------------
// Kernel 2: MFMA flash attention, 32-key rounds, 3-buffer K/V rotation,
// double-buffered P, ONE barrier per round: stage(r+1) || E(r) || PV(r-1).
// Wave w: E for query-tile w (16 q x 32 k), PV for all 64 q x its 64 channels.
// ---------------------------------------------------------------------------
#define AV_OFF 0        // 3 x 16384 (V^T tile [256c][32k] bf16)
#define AK_OFF 49152    // 3 x 4096  (kh 2048 | kl 2048)
#define AP_OFF 61440    // 2 x 5120  (64 q rows x 80 B)
#define AS_OFF 71680    // 64 floats

__global__ __launch_bounds__(256, 2) void attn_kernel(
    const unsigned short* __restrict__ qh, const unsigned short* __restrict__ ql,
    const unsigned short* __restrict__ kh, const unsigned short* __restrict__ kl,
    const unsigned short* __restrict__ vt, const float* __restrict__ gptr,
    float* __restrict__ out)
{
    __shared__ __align__(16) unsigned char smem[71936];
    const int t    = threadIdx.x;
    const int lane = t & 63;
    const int w    = t >> 6;
    const int l16  = lane & 15;
    const int quad = lane >> 4;
    const int b    = blockIdx.x & 7;            // batch -> XCD swizzle
    const int n0   = (blockIdx.x >> 3) << 6;

    // this wave's 16-query hi/lo fragments (held all kernel)
    const size_t qrow = (size_t)b * NN + n0 + w * 16 + l16;
    const bf16x8 qhA = *(const bf16x8*)(qh + qrow * 32 + quad * 8);
    const bf16x8 qlA = *(const bf16x8*)(ql + qrow * 32 + quad * 8);

    // per-thread staging pointers (advance per round)
    const unsigned char* ksrc;
    int kdst;
    {
        int c = t & 127, kr = c >> 2, cl = c & 3;
        int cg = cl ^ ((kr >> 1) & 3);
        ksrc = (const unsigned char*)((t < 128) ? kh : kl)
             + (size_t)b * NN * 64 + (size_t)kr * 64 + cg * 16;
        kdst = AK_OFF + (t >> 7) * 2048 + c * 16;
    }
    const unsigned char* vsrc;
    {
        int vr = t >> 2, cl = t & 3;
        int cg = cl ^ (vr & 3);
        vsrc = (const unsigned char*)vt + (size_t)b * CH * NN * 2
             + (size_t)vr * 8192 + cg * 16;
    }

    f32x4 acc[4][4] = {};
    float S[4] = {};

    // prologue: stage round 0 into buffer 0
    {
        gload16(ksrc, smem + kdst);
        unsigned char* vd = smem + AV_OFF + t * 16;
        gload16(vsrc,           vd);
        gload16(vsrc + 524288,  vd + 4096);    // +64 rows * 8192 B
        gload16(vsrc + 1048576, vd + 8192);
        gload16(vsrc + 1572864, vd + 12288);
    }
    __syncthreads();

    int bprv = 2, bcur = 0, bnxt = 1, pcur = 0;
    const int koffbase = (quad ^ ((l16 >> 1) & 3)) * 16;
    const int voffbase = (quad ^ (l16 & 3)) * 16;

    #pragma unroll 1
    for (int r = 0; r < 128; ++r) {
        if (r < 127) {   // stage(r+1) -> bnxt (in flight through this round)
            const unsigned char* ks = ksrc + (size_t)(r + 1) * 2048;
            gload16(ks, smem + bnxt * 4096 + kdst);
            const unsigned char* vs = vsrc + (size_t)(r + 1) * 64;
            unsigned char* vd = smem + AV_OFF + bnxt * 16384 + t * 16;
            gload16(vs,           vd);
            gload16(vs + 524288,  vd + 4096);
            gload16(vs + 1048576, vd + 8192);
            gload16(vs + 1572864, vd + 12288);
        }
        {   // E(r): this wave's 16 queries x 32 keys
            const unsigned char* kb = smem + AK_OFF + bcur * 4096;
            unsigned char* pb = smem + AP_OFF + pcur * 5120;
            #pragma unroll
            for (int kt = 0; kt < 2; ++kt) {
                int ko = (kt * 16 + l16) * 64 + koffbase;
                bf16x8 bh = *(const bf16x8*)(kb + ko);
                bf16x8 bl = *(const bf16x8*)(kb + 2048 + ko);
                f32x4 e = { 0.f, 0.f, 0.f, 0.f };
                e = MFMA16(qhA, bh, e);
                e = MFMA16(qlA, bh, e);
                e = MFMA16(qhA, bl, e);
                #pragma unroll
                for (int rr = 0; rr < 4; ++rr) {
                    float p = __expf(e[rr]);   // |e| << 88: no max needed
                    unsigned short pv16 = f2bf(p);
                    S[rr] += bf2f(pv16);       // numerator-consistent S
                    *(unsigned short*)(pb + (w * 16 + quad * 4 + rr) * 80
                                          + (kt * 16 + l16) * 2) = pv16;
                }
            }
        }
        if (r > 0) {   // PV(r-1): all 64 q x this wave's 64 channels
            const unsigned char* pp = smem + AP_OFF + (pcur ^ 1) * 5120;
            const unsigned char* vb = smem + AV_OFF + bprv * 16384;
            bf16x8 aP[4], bV[4];
            #pragma unroll
            for (int qt = 0; qt < 4; ++qt)
                aP[qt] = *(const bf16x8*)(pp + (qt * 16 + l16) * 80 + quad * 16);
            #pragma unroll
            for (int ct = 0; ct < 4; ++ct)
                bV[ct] = *(const bf16x8*)(vb + (w * 64 + ct * 16 + l16) * 64 + voffbase);
            #pragma unroll
            for (int qt = 0; qt < 4; ++qt)
                #pragma unroll
                for (int ct = 0; ct < 4; ++ct)
                    acc[qt][ct] = MFMA16(aP[qt], bV[ct], acc[qt][ct]);
        }
        __syncthreads();
        bprv = bcur; bcur = bnxt; ++bnxt; if (bnxt == 3) bnxt = 0;
        pcur ^= 1;
    }
    {   // final PV(127)
        const unsigned char* pp = smem + AP_OFF + (pcur ^ 1) * 5120;
        const unsigned char* vb = smem + AV_OFF + bprv * 16384;
        bf16x8 aP[4], bV[4];
        #pragma unroll
        for (int qt = 0; qt < 4; ++qt)
            aP[qt] = *(const bf16x8*)(pp + (qt * 16 + l16) * 80 + quad * 16);
        #pragma unroll
        for (int ct = 0; ct < 4; ++ct)
            bV[ct] = *(const bf16x8*)(vb + (w * 64 + ct * 16 + l16) * 64 + voffbase);
        #pragma unroll
        for (int qt = 0; qt < 4; ++qt)
            #pragma unroll
            for (int ct = 0; ct < 4; ++ct)
                acc[qt][ct] = MFMA16(aP[qt], bV[ct], acc[qt][ct]);
    }

    // S: reduce over 16 key-lanes (in-quad), publish per-query sums
    #pragma unroll
    for (int mask = 1; mask <= 8; mask <<= 1)
        #pragma unroll
        for (int rr = 0; rr < 4; ++rr)
            S[rr] += __shfl_xor(S[rr], mask);
    float* SM = (float*)(smem + AS_OFF);
    __syncthreads();
    if (l16 == 0) {
        #pragma unroll
        for (int rr = 0; rr < 4; ++rr)
            SM[w * 16 + quad * 4 + rr] = S[rr];
    }
    __syncthreads();

    const float g1 = 1.f + gptr[0];
    float* ob = out + (size_t)b * CH * NN;
    #pragma unroll
    for (int qt = 0; qt < 4; ++qt) {
        float is[4];
        #pragma unroll
        for (int rr = 0; rr < 4; ++rr)
            is[rr] = g1 / SM[qt * 16 + quad * 4 + rr];
        #pragma unroll
        for (int ct = 0; ct < 4; ++ct) {
            float4 o4;
            o4.x = floorf(acc[qt][ct][0] * is[0] * 256.f) * 0.00390625f;
            o4.y = floorf(acc[qt][ct][1] * is[1] * 256.f) * 0.00390625f;
            o4.z = floorf(acc[qt][ct][2] * is[2] * 256.f) * 0.00390625f;
            o4.w = floorf(acc[qt][ct][3] * is[3] * 256.f) * 0.00390625f;
            *(float4*)(ob + (size_t)(w * 64 + ct * 16 + l16) * NN
                          + n0 + qt * 16 + quad * 4) = o4;
        }
    }
}

// ---------------------------------------------------------------------------
extern "C" void kernel_launch(void* const* d_in, const int* in_sizes, int n_in,
                              void* d_out, int out_size, void* d_ws, size_t ws_size,
                              hipStream_t stream) {
    const float* x  = (const float*)d_in[0];
    const float* wq = (const float*)d_in[1];
    const float* bq = (const float*)d_in[2];
    const float* wk = (const float*)d_in[3];
    const float* bk = (const float*)d_in[4];
    const float* wv = (const float*)d_in[5];
    const float* bv = (const float*)d_in[6];
    const float* gm = (const float*)d_in[7];
    float* out = (float*)d_out;

    unsigned short* ws = (unsigned short*)d_ws;
    const size_t WSZ = 320 * 256;
    const size_t QSZ = (size_t)BB * NN * 32;
    unsigned short* wh = ws;
    unsigned short* wl = wh + WSZ;
    unsigned short* qh = wl + WSZ;
    unsigned short* ql = qh + QSZ;
    unsigned short* kh = ql + QSZ;
    unsigned short* kl = kh + QSZ;
    unsigned short* vt = kl + QSZ;

    wsplit_kernel<<<320, 256, 0, stream>>>(wq, wk, wv, wh, wl);
    proj_kernel<<<512, 256, 0, stream>>>(x, wh, wl, bq, bk, bv,
                                         qh, ql, kh, kl, vt);
    attn_kernel<<<512, 256, 0, stream>>>(qh, ql, kh, kl, vt, gm, out);
}